// Round 7
// baseline (156.744 us; speedup 1.0000x reference)
//
#include <hip/hip_runtime.h>
#include <math.h>

#define DF 512

typedef __attribute__((ext_vector_type(8))) short bf16x8;

__device__ __constant__ int c_lidx[16] = {0,1,1,1,2,2,2,2,2,3,3,3,3,3,3,3};

__device__ inline float bf2f(unsigned short s) {
    union { unsigned int u; float f; } x;
    x.u = ((unsigned int)s) << 16;
    return x.f;
}
__device__ inline unsigned short f2bf(float f) {
    union { float f; unsigned int u; } x; x.f = f;
    unsigned int r = x.u + 0x7fffu + ((x.u >> 16) & 1u);
    return (unsigned short)(r >> 16);
}

// K0: fused zero-fill (cnt, yacc, out)
__global__ void k_zero(uint4* __restrict__ a, int na,
                       uint4* __restrict__ b, int nb,
                       float* __restrict__ out)
{
    int i = blockIdx.x * blockDim.x + threadIdx.x;
    uint4 z = make_uint4(0, 0, 0, 0);
    if (i == 0) out[0] = 0.0f;
    if (i < na) { a[i] = z; return; }
    int j = i - na;
    if (j < nb) b[j] = z;
}

// v[r] = dot(w[r,:], ow) — one wave per row (used for lw1->vtmp and lw0->wv0)
__global__ __launch_bounds__(512) void k_matvec(const float* __restrict__ w,
                                                const float* __restrict__ ow,
                                                float* __restrict__ v)
{
    int r = blockIdx.x * 8 + (threadIdx.x >> 6);
    int lane = threadIdx.x & 63;
    const float* row = w + (size_t)r * DF;
    float s = 0.0f;
    #pragma unroll
    for (int j = 0; j < 8; j++) s += row[lane + j*64] * ow[lane + j*64];
    #pragma unroll
    for (int off = 32; off > 0; off >>= 1) s += __shfl_xor(s, off, 64);
    if (lane == 0) v[r] = s;
}

// u1[c*16+m] = sum_d tw1[l(m)][c][d]*v[d*16+m]; hb[m] = sum_c lb0[c*16+m]*u1[c*16+m];
// out += N*( (lb1+lb0).ow + ob )
__global__ __launch_bounds__(512) void k_pre2(const float* __restrict__ tw1,
                                              const float* __restrict__ lb1,
                                              const float* __restrict__ lb0,
                                              const float* __restrict__ ow,
                                              const float* __restrict__ ob,
                                              const float* __restrict__ v,
                                              float* __restrict__ u1,
                                              float* __restrict__ hb,
                                              float* __restrict__ out, int N)
{
    __shared__ float vs[DF];
    __shared__ float red[DF];
    __shared__ float us[DF];
    int t = threadIdx.x;
    vs[t] = v[t];
    red[t] = (lb1[t] + lb0[t]) * ow[t];
    __syncthreads();
    int c = t >> 4, m = t & 15, l = c_lidx[m];
    float u = 0.0f;
    #pragma unroll
    for (int d = 0; d < 32; d++) u += tw1[l*1024 + c*32 + d] * vs[d*16 + m];
    u1[t] = u;
    us[t] = u;
    __syncthreads();
    for (int s = 256; s > 0; s >>= 1) {
        if (t < s) red[t] += red[t + s];
        __syncthreads();
    }
    if (t < 16) {
        float s = 0.0f;
        #pragma unroll
        for (int cc = 0; cc < 32; cc++) s += lb0[cc*16 + t] * us[cc*16 + t];
        hb[t] = s;
    }
    if (t == 0) atomicAdd(out, (float)N * (red[0] + ob[0]));
}

// Gt[m][k] = sum_c lw0[k, c*16+m] * u1[c*16+m]
__global__ void k_Gt(const float* __restrict__ lw0, const float* __restrict__ u1,
                     float* __restrict__ Gt)
{
    int g = blockIdx.x * 256 + threadIdx.x;   // 8192
    int k = g >> 4, m = g & 15;
    float s = 0.0f;
    #pragma unroll
    for (int c = 0; c < 32; c++) s += lw0[(size_t)k*DF + c*16 + m] * u1[c*16 + m];
    Gt[m*DF + k] = s;
}

// per-element tables: embdot[a] = emb[a].ow ; hf[a][m] = hb[m] + sum_c emb[a,c*16+m]*u1[c*16+m]
__global__ __launch_bounds__(256) void k_helem(const float* __restrict__ emb,
                                               const float* __restrict__ ow,
                                               const float* __restrict__ u1,
                                               const float* __restrict__ hb,
                                               float* __restrict__ hf,
                                               float* __restrict__ embdot)
{
    __shared__ float r1[256];
    __shared__ float r2[DF];
    int a = blockIdx.x, t = threadIdx.x;
    float e0 = emb[(size_t)a*DF + t];
    float e1 = emb[(size_t)a*DF + t + 256];
    r1[t] = e0*ow[t] + e1*ow[t+256];
    r2[t] = e0*u1[t];
    r2[t+256] = e1*u1[t+256];
    __syncthreads();
    for (int s = 128; s > 0; s >>= 1) {
        if (t < s) r1[t] += r1[t + s];
        __syncthreads();
    }
    if (t < 16) {
        float s = hb[t];
        #pragma unroll
        for (int c = 0; c < 32; c++) s += r2[c*16 + t];
        hf[(size_t)a*16 + t] = s;
    }
    if (t == 0) embdot[a] = r1[0];
}

// K2: per-ELEMENT tensor-product: tfe[a, d*16+m] = bf16( sum_c emb[a][c*16+m] * tw0[l(m)][c][d] )
__global__ __launch_bounds__(256) void k_tf_elem(const float* __restrict__ emb,
                                                 const float* __restrict__ w0,
                                                 unsigned short* __restrict__ tfe, int NE)
{
    __shared__ float nf[DF];
    __shared__ float w[4*32*32];
    int a = blockIdx.x;
    int t = threadIdx.x;
    nf[t]       = emb[(size_t)a*DF + t];
    nf[t + 256] = emb[(size_t)a*DF + t + 256];
    for (int i = t; i < 4096; i += 256) w[i] = w0[i];
    __syncthreads();
    #pragma unroll
    for (int rep = 0; rep < 2; rep++) {
        int f = t + rep*256;
        int d = f >> 4, m = f & 15;
        int l = c_lidx[m];
        const float* wl = &w[l*1024 + d];
        float acc = 0.0f;
        #pragma unroll
        for (int c = 0; c < 32; c++) acc += nf[c*16 + m] * wl[c*32];
        tfe[(size_t)a*DF + f] = f2bf(acc);
    }
}

// histogram of dst
__global__ void k_hist(const int* __restrict__ dst, int* __restrict__ cnt, int E)
{
    int e = blockIdx.x * blockDim.x + threadIdx.x;
    if (e < E) atomicAdd(&cnt[dst[e]], 1);
}

// single-block exclusive scan (4 elems/thread): cnt[0..N) -> rp[0..N]; cnt becomes cursor
__global__ __launch_bounds__(1024) void k_scan(int* __restrict__ cnt,
                                               int* __restrict__ rp, int N, int E)
{
    __shared__ int wsum[16];
    __shared__ int sh_total;
    __shared__ int sh_carry;
    int t = threadIdx.x;
    int lane = t & 63, wv = t >> 6;
    if (t == 0) sh_carry = 0;
    __syncthreads();
    for (int base = 0; base < N; base += 4096) {
        int i0 = base + t*4;
        int v0 = (i0+0 < N) ? cnt[i0+0] : 0;
        int v1 = (i0+1 < N) ? cnt[i0+1] : 0;
        int v2 = (i0+2 < N) ? cnt[i0+2] : 0;
        int v3 = (i0+3 < N) ? cnt[i0+3] : 0;
        int s0 = v0, s1 = s0+v1, s2 = s1+v2, tot = s2+v3;
        int v = tot;
        #pragma unroll
        for (int off = 1; off < 64; off <<= 1) {
            int x = __shfl_up(v, off, 64);
            if (lane >= off) v += x;
        }
        if (lane == 63) wsum[wv] = v;
        __syncthreads();
        if (t < 16) {
            int x = wsum[t];
            int incl = x;
            #pragma unroll
            for (int off = 1; off < 16; off <<= 1) {
                int y = __shfl_up(incl, off, 16);
                if (t >= off) incl += y;
            }
            wsum[t] = incl - x;
            if (t == 15) sh_total = incl;
        }
        __syncthreads();
        int excl = sh_carry + wsum[wv] + (v - tot);
        if (i0+0 < N) { rp[i0+0] = excl;      cnt[i0+0] = excl; }
        if (i0+1 < N) { rp[i0+1] = excl + s0; cnt[i0+1] = excl + s0; }
        if (i0+2 < N) { rp[i0+2] = excl + s1; cnt[i0+2] = excl + s1; }
        if (i0+3 < N) { rp[i0+3] = excl + s2; cnt[i0+3] = excl + s2; }
        __syncthreads();
        if (t == 0) sh_carry += sh_total;
        __syncthreads();
    }
    if (t == 0) rp[N] = E;
}

// K1': compute SH per edge, scatter directly into CSR slots: Yp[p], sA[p], aA[p]
__global__ void k_fill_sh(const float* __restrict__ pos,
                          const int* __restrict__ src,
                          const int* __restrict__ dst,
                          const int* __restrict__ an,
                          const float* __restrict__ cell,
                          int* __restrict__ cur,
                          float* __restrict__ Yp,
                          int* __restrict__ sA,
                          int* __restrict__ aA, int E)
{
    int e = blockIdx.x * blockDim.x + threadIdx.x;
    if (e >= E) return;
    int s = src[e], d = dst[e];
    float cx = cell[0], cy = cell[4], cz = cell[8];
    float ex = pos[d*3+0] - pos[s*3+0];
    float ey = pos[d*3+1] - pos[s*3+1];
    float ez = pos[d*3+2] - pos[s*3+2];
    ex -= rintf(ex/cx)*cx;
    ey -= rintf(ey/cy)*cy;
    ez -= rintf(ez/cz)*cz;
    float len = fmaxf(sqrtf(ex*ex + ey*ey + ez*ez), 1e-8f);
    float x = ex/len, y = ey/len, z = ez/len;
    float x2 = x*x, y2 = y*y, z2 = z*z;
    float o[16];
    o[0]  = 0.28209479177387814f;
    o[1]  = 0.4886025119029199f*y;
    o[2]  = 0.4886025119029199f*z;
    o[3]  = 0.4886025119029199f*x;
    o[4]  = 1.0925484305920792f*x*y;
    o[5]  = 1.0925484305920792f*y*z;
    o[6]  = 0.31539156525252005f*(3.0f*z2 - 1.0f);
    o[7]  = 1.0925484305920792f*x*z;
    o[8]  = 0.5462742152960396f*(x2 - y2);
    o[9]  = 0.5900435899266435f*y*(3.0f*x2 - y2);
    o[10] = 2.890611442640554f*x*y*z;
    o[11] = 0.4570457994644658f*y*(5.0f*z2 - 1.0f);
    o[12] = 0.3731763325901154f*z*(5.0f*z2 - 3.0f);
    o[13] = 0.4570457994644658f*x*(5.0f*z2 - 1.0f);
    o[14] = 1.445305721320277f*z*(x2 - y2);
    o[15] = 0.5900435899266435f*x*(x2 - 3.0f*y2);
    int p = atomicAdd(&cur[d], 1);
    float4* yo = (float4*)(Yp + (size_t)p*16);
    yo[0] = make_float4(o[0],o[1],o[2],o[3]);
    yo[1] = make_float4(o[4],o[5],o[6],o[7]);
    yo[2] = make_float4(o[8],o[9],o[10],o[11]);
    yo[3] = make_float4(o[12],o[13],o[14],o[15]);
    sA[p] = s;
    aA[p] = an[s];
}

// yacc[n, m] += Yp[p, m] for n = sA[p]  (one independent atomic per thread)
__global__ void k_yacc(const float* __restrict__ Yp, const int* __restrict__ sA,
                       float* __restrict__ yacc, int E)
{
    int g = blockIdx.x * blockDim.x + threadIdx.x;
    if (g >= E * 16) return;
    int p = g >> 4, m = g & 15;
    atomicAdd(&yacc[(size_t)sA[p]*16 + m], Yp[g]);
}

// K3'': CSR aggregation + FULL energy epilogue (no agg materialization, no GEMM).
// per node n (one wave):
//   acc[f] = sum_{in-edges} Yp[i, f&15] * tfe[aA[i], f]           (f = lane*8..+7)
//   s  = acc . wv0                                                 (S1 gemm part)
//      + sum_m ( acc . Gt[m,:] ) * yacc[n,m]                       (S2 gemm part)
//   lane0: s += embdot[an[n]] + sum_m hf[an[n],m]*yacc[n,m]
__device__ inline void agg_edge(const unsigned short* __restrict__ tfe,
                                const float* __restrict__ Yp,
                                int i, int a, int f0, int yoff, float* acc)
{
    bf16x8 v = *(const bf16x8*)(tfe + (size_t)a*DF + f0);
    const float4* q = (const float4*)(Yp + (size_t)i*16 + yoff);
    float4 y0 = q[0], y1 = q[1];
    acc[0] += bf2f((unsigned short)v[0])*y0.x;
    acc[1] += bf2f((unsigned short)v[1])*y0.y;
    acc[2] += bf2f((unsigned short)v[2])*y0.z;
    acc[3] += bf2f((unsigned short)v[3])*y0.w;
    acc[4] += bf2f((unsigned short)v[4])*y1.x;
    acc[5] += bf2f((unsigned short)v[5])*y1.y;
    acc[6] += bf2f((unsigned short)v[6])*y1.z;
    acc[7] += bf2f((unsigned short)v[7])*y1.w;
}

__global__ __launch_bounds__(256) void k_agg_final(const unsigned short* __restrict__ tfe,
                                                   const float* __restrict__ Yp,
                                                   const int* __restrict__ rp,
                                                   const int* __restrict__ aA,
                                                   const int* __restrict__ an,
                                                   const float* __restrict__ yacc,
                                                   const float* __restrict__ hf,
                                                   const float* __restrict__ embdot,
                                                   const float* __restrict__ Gt,
                                                   const float* __restrict__ wv0,
                                                   float* __restrict__ out, int N)
{
    __shared__ float sGt[16][DF];   // 32 KB
    __shared__ float swv[DF];       // 2 KB
    __shared__ float wred[4];
    int t = threadIdx.x;
    {
        float4* sg = (float4*)&sGt[0][0];
        const float4* gg = (const float4*)Gt;
        for (int i = t; i < 16*DF/4; i += 256) sg[i] = gg[i];
        float4* sw = (float4*)swv;
        const float4* gw = (const float4*)wv0;
        if (t < DF/4) sw[t] = gw[t];
    }
    __syncthreads();
    int lane = t & 63, w = t >> 6;
    int f0 = lane * 8, yoff = f0 & 15;
    float bsum = 0.0f;
    for (int n = blockIdx.x*4 + w; n < N; n += gridDim.x*4) {
        int beg = rp[n], end = rp[n+1];
        float acc[8] = {0,0,0,0,0,0,0,0};
        int i = beg;
        for (; i + 1 < end; i += 2) {
            agg_edge(tfe, Yp, i,   aA[i],   f0, yoff, acc);
            agg_edge(tfe, Yp, i+1, aA[i+1], f0, yoff, acc);
        }
        if (i < end) agg_edge(tfe, Yp, i, aA[i], f0, yoff, acc);

        float ym[16];
        {
            const float4* yr = (const float4*)(yacc + (size_t)n*16);
            float4 a0 = yr[0], a1 = yr[1], a2 = yr[2], a3 = yr[3];
            ym[0]=a0.x; ym[1]=a0.y; ym[2]=a0.z; ym[3]=a0.w;
            ym[4]=a1.x; ym[5]=a1.y; ym[6]=a1.z; ym[7]=a1.w;
            ym[8]=a2.x; ym[9]=a2.y; ym[10]=a2.z; ym[11]=a2.w;
            ym[12]=a3.x; ym[13]=a3.y; ym[14]=a3.z; ym[15]=a3.w;
        }
        float s;
        {
            const float4* wp = (const float4*)&swv[f0];
            float4 w0v = wp[0], w1v = wp[1];
            s = acc[0]*w0v.x + acc[1]*w0v.y + acc[2]*w0v.z + acc[3]*w0v.w
              + acc[4]*w1v.x + acc[5]*w1v.y + acc[6]*w1v.z + acc[7]*w1v.w;
        }
        #pragma unroll
        for (int m = 0; m < 16; m++) {
            const float4* gp = (const float4*)&sGt[m][f0];
            float4 g0 = gp[0], g1 = gp[1];
            float pm = acc[0]*g0.x + acc[1]*g0.y + acc[2]*g0.z + acc[3]*g0.w
                     + acc[4]*g1.x + acc[5]*g1.y + acc[6]*g1.z + acc[7]*g1.w;
            s += pm * ym[m];
        }
        #pragma unroll
        for (int off = 32; off > 0; off >>= 1) s += __shfl_xor(s, off, 64);
        if (lane == 0) {
            int a = an[n];
            const float* hp = hf + (size_t)a*16;
            float s2 = embdot[a];
            #pragma unroll
            for (int m = 0; m < 16; m++) s2 += hp[m] * ym[m];
            bsum += s + s2;
        }
    }
    if (lane == 0) wred[w] = bsum;
    __syncthreads();
    if (t == 0) atomicAdd(out, wred[0] + wred[1] + wred[2] + wred[3]);
}

extern "C" void kernel_launch(void* const* d_in, const int* in_sizes, int n_in,
                              void* d_out, int out_size, void* d_ws, size_t ws_size,
                              hipStream_t stream)
{
    const float* pos  = (const float*)d_in[0];
    const float* cell = (const float*)d_in[1];
    const int*   an   = (const int*)d_in[2];
    const int*   ei   = (const int*)d_in[3];
    const float* emb  = (const float*)d_in[4];
    const float* tw0  = (const float*)d_in[5];
    const float* lw0  = (const float*)d_in[6];
    const float* lb0  = (const float*)d_in[7];
    const float* tw1  = (const float*)d_in[8];
    const float* lw1  = (const float*)d_in[9];
    const float* lb1  = (const float*)d_in[10];
    const float* ow   = (const float*)d_in[11];
    const float* ob   = (const float*)d_in[12];
    int N  = in_sizes[0] / 3;
    int E  = in_sizes[3] / 2;
    int NE = in_sizes[4] / DF;   // 89 elements
    const int* src = ei;
    const int* dst = ei + E;

    char* ws = (char*)d_ws;
    size_t off = 0;
    auto alloc = [&](size_t bytes) { void* p = ws + off; off += (bytes + 255) / 256 * 256; return p; };

    float* Yp           = (float*)alloc((size_t)E * 16 * 4);
    int*   sA           = (int*)alloc((size_t)E * 4);
    int*   aA           = (int*)alloc((size_t)E * 4);
    unsigned short* tfe = (unsigned short*)alloc((size_t)NE * DF * 2);
    float* u1     = (float*)alloc(DF * 4);
    float* vtmp   = (float*)alloc(DF * 4);
    float* wv0    = (float*)alloc(DF * 4);
    float* hb     = (float*)alloc(16 * 4);
    float* Gt     = (float*)alloc(16 * DF * 4);
    float* hf     = (float*)alloc((size_t)NE * 16 * 4);
    float* embdot = (float*)alloc((size_t)NE * 4);
    float* yacc   = (float*)alloc((size_t)N * 16 * 4);
    int*   cnt    = (int*)alloc((size_t)N * 4);
    int*   rp     = (int*)alloc((size_t)(N + 1) * 4);

    float* out = (float*)d_out;

    int na = (N * 4) / 16;
    int nb = (N * 64) / 16;
    k_zero<<<(na + nb + 255) / 256, 256, 0, stream>>>((uint4*)cnt, na, (uint4*)yacc, nb, out);

    k_matvec<<<DF / 8, 512, 0, stream>>>(lw1, ow, vtmp);
    k_matvec<<<DF / 8, 512, 0, stream>>>(lw0, ow, wv0);
    k_pre2<<<1, 512, 0, stream>>>(tw1, lb1, lb0, ow, ob, vtmp, u1, hb, out, N);
    k_Gt<<<(16 * DF) / 256, 256, 0, stream>>>(lw0, u1, Gt);
    k_helem<<<NE, 256, 0, stream>>>(emb, ow, u1, hb, hf, embdot);
    k_hist<<<(E + 255) / 256, 256, 0, stream>>>(dst, cnt, E);
    k_scan<<<1, 1024, 0, stream>>>(cnt, rp, N, E);
    k_fill_sh<<<(E + 255) / 256, 256, 0, stream>>>(pos, src, dst, an, cell, cnt, Yp, sA, aA, E);
    k_tf_elem<<<NE, 256, 0, stream>>>(emb, tw0, tfe, NE);
    k_yacc<<<(E * 16 + 255) / 256, 256, 0, stream>>>(Yp, sA, yacc, E);
    k_agg_final<<<1024, 256, 0, stream>>>(tfe, Yp, rp, aA, an, yacc, hf, embdot, Gt, wv0, out, N);
}